// Round 1
// baseline (1580.778 us; speedup 1.0000x reference)
//
#include <hip/hip_runtime.h>

#define BB 4
#define CH 64
#define HH 96
#define WW 96
#define DD 8
#define NS 243   // (2D+1)*(2S+1)^2 = 3*9*9
#define CC 4     // c-chunk staged in LDS

// ---------------------------------------------------------------------------
// Kernel 1: per-pixel masks. mask = clip(sum_d alpha, 0, 1), shape (B,H,W)
// ---------------------------------------------------------------------------
__global__ void masks_kernel(const float* __restrict__ a1,
                             const float* __restrict__ a2,
                             float* __restrict__ m1,
                             float* __restrict__ m2) {
    int p = blockIdx.x * 256 + threadIdx.x;
    if (p >= BB * HH * WW) return;
    float4 x0 = ((const float4*)a1)[p * 2];
    float4 x1 = ((const float4*)a1)[p * 2 + 1];
    float4 y0 = ((const float4*)a2)[p * 2];
    float4 y1 = ((const float4*)a2)[p * 2 + 1];
    float s1 = ((x0.x + x0.y) + (x0.z + x0.w)) + ((x1.x + x1.y) + (x1.z + x1.w));
    float s2 = ((y0.x + y0.y) + (y0.z + y0.w)) + ((y1.x + y1.y) + (y1.z + y1.w));
    m1[p] = fminf(fmaxf(s1, 0.0f), 1.0f);
    m2[p] = fminf(fmaxf(s2, 0.0f), 1.0f);
}

// ---------------------------------------------------------------------------
// Kernel 2: cost_volume_mask output (B, NS, H, W, D), 287 MB, write-bound.
// block = 768 threads = one (x,z) plane row; grid = B*NS*H. Coalesced stores.
// ---------------------------------------------------------------------------
__global__ void maskvol_kernel(const float* __restrict__ m1,
                               const float* __restrict__ m2,
                               float* __restrict__ out) {
    int bi = blockIdx.x;                 // = (b*NS + s)*H + y
    int y = bi % HH;
    int s = (bi / HH) % NS;
    int b = bi / (HH * NS);
    int k = s / 81;
    int i = (s / 9) % 9;
    int j = s % 9;
    int t = threadIdx.x;
    int x = t >> 3;
    int z = t & 7;
    int yy = y + i - 4;
    int xx = x + j - 4;
    int zz = z + k - 1;
    float m1v = m1[(b * HH + y) * WW + x];
    float mv = 1.0f;  // pad value for the mask is 1.0
    if (yy >= 0 && yy < HH && xx >= 0 && xx < WW && zz >= 0 && zz < DD)
        mv = m2[(b * HH + yy) * WW + xx];
    float r = m1v * mv;
    out[(size_t)bi * (WW * DD) + t] = fminf(fmaxf(r, 0.0f), 1.0f);
}

// ---------------------------------------------------------------------------
// Kernel 3: cost volume. WG = (i, y, b); 192 threads = 24 xb * 8 z.
// Per-thread register tile: acc[k=3][j=9][t=4] over the c-dot (108 accs).
// LDS layout [c][z][x] (x contiguous) -> ds_read_b128 everywhere.
// f2 staged with z pad planes ({-1,8} -> 0) and x halo (+-4 -> 0) so the
// inner loop has no bounds checks (feature pad value is 0).
// ---------------------------------------------------------------------------
__global__ __launch_bounds__(192, 3)
void cost_kernel(const float* __restrict__ f1,
                 const float* __restrict__ f2,
                 float* __restrict__ out) {
    const int i   = blockIdx.x;   // 0..8
    const int y   = blockIdx.y;   // 0..95
    const int b   = blockIdx.z;   // 0..3
    const int tid = threadIdx.x;  // 0..191
    const int xb  = tid >> 3;     // 0..23  (x block of 4)
    const int z   = tid & 7;      // 0..7

    const int yp = y + i - 4;     // source row in f2 (may be out of range)

    // ---- fast path: whole row padded with zeros -> cost == 0 ----
    if (yp < 0 || yp >= HH) {
        #pragma unroll
        for (int k = 0; k < 3; ++k)
            #pragma unroll
            for (int j = 0; j < 9; ++j) {
                int s = k * 81 + i * 9 + j;
                size_t base = (((size_t)(b * NS + s) * HH + y) * WW) * DD;
                #pragma unroll
                for (int t = 0; t < 4; ++t)
                    out[base + (size_t)(xb * 4 + t) * DD + z] = 0.0f;
            }
        return;
    }

    __shared__ __align__(16) float f1s[CC][8][96];     // [c][z][x]
    __shared__ __align__(16) float f2s[CC][10][104];   // [c][z'+1][x'+4]

    // zero f2s once (halo regions persist across chunks; interior rewritten)
    for (int n = tid; n < CC * 10 * 104; n += 192)
        ((float*)f2s)[n] = 0.0f;

    const int th96 = (tid < 96) ? tid : tid - 96;   // tid % 96
    const int td96 = (tid < 96) ? 0 : 1;            // tid / 96

    float acc[3][9][4];
    #pragma unroll
    for (int k = 0; k < 3; ++k)
        #pragma unroll
        for (int j = 0; j < 9; ++j)
            #pragma unroll
            for (int t = 0; t < 4; ++t)
                acc[k][j][t] = 0.0f;

    for (int c0 = 0; c0 < CH; c0 += CC) {
        __syncthreads();  // previous chunk's reads done before overwrite
        // stage f1 row (y) and f2 row (yp), x-minor so LDS writes are
        // conflict-free; global pattern is 32B-strided but L1-absorbed.
        #pragma unroll
        for (int n = 0; n < 16; ++n) {          // CC*768/192 iterations
            int c  = n >> 2;
            int zz = ((n & 3) << 1) + td96;
            const size_t g1 = (((size_t)(b * CH + c0 + c) * HH + y) * WW + th96) * DD + zz;
            f1s[c][zz][th96] = f1[g1];
        }
        #pragma unroll
        for (int n = 0; n < 16; ++n) {
            int c  = n >> 2;
            int zz = ((n & 3) << 1) + td96;
            const size_t g2 = (((size_t)(b * CH + c0 + c) * HH + yp) * WW + th96) * DD + zz;
            f2s[c][zz + 1][th96 + 4] = f2[g2];
        }
        __syncthreads();

        #pragma unroll
        for (int c = 0; c < CC; ++c) {
            float4 f1v = *(const float4*)&f1s[c][z][xb * 4];
            float f1a[4] = {f1v.x, f1v.y, f1v.z, f1v.w};
            #pragma unroll
            for (int k = 0; k < 3; ++k) {
                // window x' in [xb*4-4, xb*4+12) at plane z' = z+k-1
                float4 w0 = *(const float4*)&f2s[c][z + k][xb * 4];
                float4 w1 = *(const float4*)&f2s[c][z + k][xb * 4 + 4];
                float4 w2 = *(const float4*)&f2s[c][z + k][xb * 4 + 8];
                float w[12] = {w0.x, w0.y, w0.z, w0.w,
                               w1.x, w1.y, w1.z, w1.w,
                               w2.x, w2.y, w2.z, w2.w};
                #pragma unroll
                for (int t = 0; t < 4; ++t)
                    #pragma unroll
                    for (int j = 0; j < 9; ++j)
                        acc[k][j][t] = fmaf(f1a[t], w[t + j], acc[k][j][t]);
            }
        }
    }

    // epilogue: scale by 1/64 (mean over c) and store
    #pragma unroll
    for (int k = 0; k < 3; ++k)
        #pragma unroll
        for (int j = 0; j < 9; ++j) {
            int s = k * 81 + i * 9 + j;
            size_t base = (((size_t)(b * NS + s) * HH + y) * WW) * DD;
            #pragma unroll
            for (int t = 0; t < 4; ++t)
                out[base + (size_t)(xb * 4 + t) * DD + z] = acc[k][j][t] * 0.015625f;
        }
}

// ---------------------------------------------------------------------------
extern "C" void kernel_launch(void* const* d_in, const int* in_sizes, int n_in,
                              void* d_out, int out_size, void* d_ws, size_t ws_size,
                              hipStream_t stream) {
    const float* f1 = (const float*)d_in[0];  // mpi1_features (4,64,96,96,8)
    const float* a1 = (const float*)d_in[1];  // mpi1_alpha    (4,1,96,96,8)
    const float* f2 = (const float*)d_in[2];  // mpi2_features
    const float* a2 = (const float*)d_in[3];  // mpi2_alpha

    float* out      = (float*)d_out;
    float* out_cost = out;                                        // (B,NS,H,W,D)
    float* out_mask = out + (size_t)BB * NS * HH * WW * DD;       // second output

    float* m1 = (float*)d_ws;                 // B*H*W floats
    float* m2 = m1 + BB * HH * WW;            // B*H*W floats (295 KB total)

    masks_kernel<<<(BB * HH * WW + 255) / 256, 256, 0, stream>>>(a1, a2, m1, m2);
    maskvol_kernel<<<BB * NS * HH, WW * DD, 0, stream>>>(m1, m2, out_mask);
    cost_kernel<<<dim3(9, HH, BB), 192, 0, stream>>>(f1, f2, out_cost);
}

// Round 2
// 964.808 us; speedup vs baseline: 1.6384x; 1.6384x over previous
//
#include <hip/hip_runtime.h>

#define BB 4
#define CH 64
#define HH 96
#define WW 96
#define DD 8
#define NS 243   // (2D+1)*(2S+1)^2 = 3*9*9
#define CC 4     // c-chunk staged in LDS

// ---------------------------------------------------------------------------
// Kernel 1: per-pixel masks. mask = clip(sum_d alpha, 0, 1), shape (B,H,W)
// ---------------------------------------------------------------------------
__global__ void masks_kernel(const float* __restrict__ a1,
                             const float* __restrict__ a2,
                             float* __restrict__ m1,
                             float* __restrict__ m2) {
    int p = blockIdx.x * 256 + threadIdx.x;
    if (p >= BB * HH * WW) return;
    float4 x0 = ((const float4*)a1)[p * 2];
    float4 x1 = ((const float4*)a1)[p * 2 + 1];
    float4 y0 = ((const float4*)a2)[p * 2];
    float4 y1 = ((const float4*)a2)[p * 2 + 1];
    float s1 = ((x0.x + x0.y) + (x0.z + x0.w)) + ((x1.x + x1.y) + (x1.z + x1.w));
    float s2 = ((y0.x + y0.y) + (y0.z + y0.w)) + ((y1.x + y1.y) + (y1.z + y1.w));
    m1[p] = fminf(fmaxf(s1, 0.0f), 1.0f);
    m2[p] = fminf(fmaxf(s2, 0.0f), 1.0f);
}

// ---------------------------------------------------------------------------
// Kernel 2: cost_volume_mask (B,NS,H,W,D), 287 MB. One block per (b,s);
// 256 threads x 72 float4 stores, fully coalesced full-line writes.
// m1/m2 are 147 KB -> L1/L2 resident.
// ---------------------------------------------------------------------------
__global__ __launch_bounds__(256)
void maskvol_kernel(const float* __restrict__ m1,
                    const float* __restrict__ m2,
                    float* __restrict__ out) {
    int bs = blockIdx.x;            // b*NS + s
    int b = bs / NS;
    int s = bs % NS;
    int k = s / 81;
    int i = (s / 9) % 9;
    int j = s % 9;
    const float* m1b = m1 + b * HH * WW;
    const float* m2b = m2 + b * HH * WW;
    float4* o4 = (float4*)out + (size_t)bs * (HH * WW * DD / 4);
    for (int n = threadIdx.x; n < HH * WW * DD / 4; n += 256) {
        int y = n / 192;            // 192 float4 per y-row
        int r = n - y * 192;
        int x = r >> 1;
        int zb = (r & 1) * 4;       // z of component q is zb+q
        float m1v = m1b[y * WW + x];
        int yy = y + i - 4;
        int xx = x + j - 4;
        float m2v = 1.0f;           // mask pad value
        if ((unsigned)yy < HH && (unsigned)xx < WW) m2v = m2b[yy * WW + xx];
        float pv = m1v * m2v;       // value when zz in range
        float4 v;
        float* vp = (float*)&v;
        #pragma unroll
        for (int q = 0; q < 4; ++q) {
            int zz = zb + q + k - 1;
            float r0 = ((unsigned)zz < DD) ? pv : m1v;  // z-pad mask = 1.0
            vp[q] = fminf(fmaxf(r0, 0.0f), 1.0f);
        }
        o4[n] = v;
    }
}

// ---------------------------------------------------------------------------
// Kernel 3: cost volume. Block = (i,y,b) via XCD-swizzled 1D grid (the 9
// i-siblings of each (b,y) stay on one XCD -> rows fetched once per XCD).
// 192 threads = 24 xb * 8 z; acc[k3][j9][x4] = 108 regs (launch_bounds(192,2)
// so they stay in VGPRs). Staging: coalesced float4 row loads + register
// prefetch of next chunk, transposed into LDS [c][z][x] (2-way bank = free).
// Compute: all ds_read_b128. Epilogue: LDS transpose -> dwordx4 stores,
// 1024B contiguous per wave (full-line writes).
// ---------------------------------------------------------------------------
__global__ __launch_bounds__(192, 2)
void cost_kernel(const float* __restrict__ f1,
                 const float* __restrict__ f2,
                 float* __restrict__ out) {
    const int L = blockIdx.x;             // 0..3455
    const int u = L % 72;
    const int i = u >> 3;                 // 0..8
    const int g = (L / 72) * 8 + (u & 7); // 0..383 = b*HH + y
    const int b = g / HH;
    const int y = g % HH;
    const int tid = threadIdx.x;
    const int xb = tid >> 3;              // 0..23
    const int z  = tid & 7;               // 0..7
    const int yp = y + i - 4;

    // ---- fast path: whole source row is zero-pad -> cost == 0 ----
    if (yp < 0 || yp >= HH) {
        #pragma unroll
        for (int k = 0; k < 3; ++k)
            #pragma unroll
            for (int j = 0; j < 9; ++j) {
                int s = k * 81 + i * 9 + j;
                float4* o4 = (float4*)out + ((size_t)(b * NS + s) * HH + y) * 192;
                o4[tid] = make_float4(0.f, 0.f, 0.f, 0.f);
            }
        return;
    }

    __shared__ __align__(16) float f1s[CC][8][96];    // [c][z][x]
    __shared__ __align__(16) float f2s[CC][10][104];  // [c][z+1][x+4], halos 0

    for (int n = tid; n < CC * 10 * 104; n += 192)
        ((float*)f2s)[n] = 0.0f;

    const int xs = tid >> 1;        // staging pixel 0..95
    const int zb = (tid & 1) * 4;   // staging z-base (float4 = z zb..zb+3)

    // row base pointers in float4 units; per-channel stride = HH*192
    const float4* f1r = (const float4*)f1 + ((size_t)(b * CH) * HH + y)  * 192;
    const float4* f2r = (const float4*)f2 + ((size_t)(b * CH) * HH + yp) * 192;

    float4 p1[CC], p2[CC];
    #pragma unroll
    for (int c = 0; c < CC; ++c) {
        p1[c] = f1r[(size_t)c * (HH * 192) + tid];
        p2[c] = f2r[(size_t)c * (HH * 192) + tid];
    }

    float acc[3][9][4];
    #pragma unroll
    for (int k = 0; k < 3; ++k)
        #pragma unroll
        for (int j = 0; j < 9; ++j)
            #pragma unroll
            for (int t = 0; t < 4; ++t)
                acc[k][j][t] = 0.0f;

    for (int c0 = 0; c0 < CH; c0 += CC) {
        __syncthreads();  // previous chunk's LDS reads complete
        #pragma unroll
        for (int c = 0; c < CC; ++c) {
            f1s[c][zb + 0][xs] = p1[c].x;
            f1s[c][zb + 1][xs] = p1[c].y;
            f1s[c][zb + 2][xs] = p1[c].z;
            f1s[c][zb + 3][xs] = p1[c].w;
            f2s[c][zb + 1][xs + 4] = p2[c].x;   // plane index = z+1
            f2s[c][zb + 2][xs + 4] = p2[c].y;
            f2s[c][zb + 3][xs + 4] = p2[c].z;
            f2s[c][zb + 4][xs + 4] = p2[c].w;
        }
        if (c0 + CC < CH) {   // prefetch next chunk; latency hidden by compute
            #pragma unroll
            for (int c = 0; c < CC; ++c) {
                p1[c] = f1r[(size_t)(c0 + CC + c) * (HH * 192) + tid];
                p2[c] = f2r[(size_t)(c0 + CC + c) * (HH * 192) + tid];
            }
        }
        __syncthreads();

        #pragma unroll
        for (int c = 0; c < CC; ++c) {
            float4 f1v = *(const float4*)&f1s[c][z][xb * 4];
            float f1a[4] = {f1v.x, f1v.y, f1v.z, f1v.w};
            #pragma unroll
            for (int k = 0; k < 3; ++k) {
                float4 w0 = *(const float4*)&f2s[c][z + k][xb * 4];
                float4 w1 = *(const float4*)&f2s[c][z + k][xb * 4 + 4];
                float4 w2 = *(const float4*)&f2s[c][z + k][xb * 4 + 8];
                float w[12] = {w0.x, w0.y, w0.z, w0.w,
                               w1.x, w1.y, w1.z, w1.w,
                               w2.x, w2.y, w2.z, w2.w};
                #pragma unroll
                for (int t = 0; t < 4; ++t)
                    #pragma unroll
                    for (int j = 0; j < 9; ++j)
                        acc[k][j][t] = fmaf(f1a[t], w[t + j], acc[k][j][t]);
            }
        }
    }

    // epilogue: per-slice LDS transpose -> fully coalesced dwordx4 stores
    __syncthreads();                // all compute reads of f1s done
    float* sbuf = (float*)f1s;      // 768-float scratch (reuse)
    #pragma unroll
    for (int k = 0; k < 3; ++k)
        #pragma unroll
        for (int j = 0; j < 9; ++j) {
            int s = k * 81 + i * 9 + j;
            #pragma unroll
            for (int t = 0; t < 4; ++t)
                sbuf[(xb * 4 + t) * 8 + z] = acc[k][j][t] * 0.015625f;
            __syncthreads();
            float4 v = *(float4*)&sbuf[tid * 4];
            float4* o4 = (float4*)out + ((size_t)(b * NS + s) * HH + y) * 192;
            o4[tid] = v;
            __syncthreads();        // before next slice overwrites sbuf
        }
}

// ---------------------------------------------------------------------------
extern "C" void kernel_launch(void* const* d_in, const int* in_sizes, int n_in,
                              void* d_out, int out_size, void* d_ws, size_t ws_size,
                              hipStream_t stream) {
    const float* f1 = (const float*)d_in[0];  // mpi1_features (4,64,96,96,8)
    const float* a1 = (const float*)d_in[1];  // mpi1_alpha    (4,1,96,96,8)
    const float* f2 = (const float*)d_in[2];  // mpi2_features
    const float* a2 = (const float*)d_in[3];  // mpi2_alpha

    float* out      = (float*)d_out;
    float* out_cost = out;                                   // (B,NS,H,W,D)
    float* out_mask = out + (size_t)BB * NS * HH * WW * DD;  // second output

    float* m1 = (float*)d_ws;                 // B*H*W floats
    float* m2 = m1 + BB * HH * WW;            // B*H*W floats (295 KB total)

    masks_kernel<<<(BB * HH * WW + 255) / 256, 256, 0, stream>>>(a1, a2, m1, m2);
    maskvol_kernel<<<BB * NS, 256, 0, stream>>>(m1, m2, out_mask);
    cost_kernel<<<3456, 192, 0, stream>>>(f1, f2, out_cost);
}